// Round 8
// baseline (10964.999 us; speedup 1.0000x reference)
//
#include <hip/hip_runtime.h>
#include <stdint.h>

typedef unsigned short u16;
typedef unsigned int u32;
typedef unsigned long long u64;

#define B_ 64
#define T_ 512
#define N_ 128
#define H_ 512
#define KDIM 640        // H + N
#define FL 32           // u32 per 128B line
// sync lines: [0..7] org counters (agent) only. Consumers poll hs data
// directly against the bf16-NaN sentinel 0x7FC0 (|h|<1 can never produce it;
// exact +-1.0 -> 0x3F80/0xBF80, still not the sentinel).

typedef __attribute__((ext_vector_type(8))) short short8;
typedef __attribute__((ext_vector_type(4))) float floatx4;
typedef __attribute__((ext_vector_type(4))) u32 u32x4;

__device__ __forceinline__ float sigf(float x) { return 1.0f / (1.0f + __expf(-x)); }
__device__ __forceinline__ float tanh_(float x) { return 1.0f - 2.0f / (1.0f + __expf(2.0f * x)); }

__device__ __forceinline__ u16 f2bf(float x) {
    u32 u = __float_as_uint(x);
    u32 r = (u + 0x7FFFu + ((u >> 16) & 1u)) >> 16;   // RNE
    return (u16)r;
}

// X [B,T,N] fp32 -> Xb [T,B,N] bf16
__global__ __launch_bounds__(256) void k_xb(const float* __restrict__ X, u16* __restrict__ Xb) {
    int i = blockIdx.x * 256 + threadIdx.x;
    int n = i & 127, b = (i >> 7) & 63, t = i >> 13;
    Xb[i] = f2bf(X[(b * T_ + t) * N_ + n]);
}

// Wcat^T [2048 cols][640 k] bf16: rows k<512 from Wh, k>=512 from Wx
__global__ __launch_bounds__(256) void k_wcat(const float* __restrict__ Wx, const float* __restrict__ Wh,
                                              u16* __restrict__ Wt) {
    int i = blockIdx.x * 256 + threadIdx.x;
    int c = i & 2047, k = i >> 11;
    float v = (k < H_) ? Wh[k * 2048 + c] : Wx[(k - H_) * 2048 + c];
    Wt[c * KDIM + k] = f2bf(v);
}

// NaN-prefill hs rows [64, 513*64): 0x7FC0 bf16 sentinel.
__global__ __launch_bounds__(256) void k_fill(uint4* __restrict__ p) {
    int i = blockIdx.x * 256 + threadIdx.x;
    uint4 v; v.x = v.y = v.z = v.w = 0x7FC07FC0u;
    p[i] = v;
}

// Full 8KB h-tile load: lane reads 16B from each of the 8 batch rows (row
// stride 1024B; coalesced: 64 lanes cover each 1KB row densely, zero dup).
// ONE asm block so the vmcnt(0) can't be separated from the loads (rule 18).
// R18: pure sc0 (L2-fresh). The old odd-round "sc0 sc1" hedge was an HBM
// read (~900cy) per odd round -- R17's counters proved sc1 bypasses L2.
#define TLOADS(SC) \
    asm volatile( \
        "global_load_dwordx4 %0, %8, off " SC "\n\t" \
        "global_load_dwordx4 %1, %8, off offset:1024 " SC "\n\t" \
        "global_load_dwordx4 %2, %8, off offset:2048 " SC "\n\t" \
        "global_load_dwordx4 %3, %8, off offset:3072 " SC "\n\t" \
        "global_load_dwordx4 %4, %9, off " SC "\n\t" \
        "global_load_dwordx4 %5, %9, off offset:1024 " SC "\n\t" \
        "global_load_dwordx4 %6, %9, off offset:2048 " SC "\n\t" \
        "global_load_dwordx4 %7, %9, off offset:3072 " SC "\n\t" \
        "s_waitcnt vmcnt(0)" \
        : "=&v"(ch[0]), "=&v"(ch[1]), "=&v"(ch[2]), "=&v"(ch[3]), \
          "=&v"(ch[4]), "=&v"(ch[5]), "=&v"(ch[6]), "=&v"(ch[7]) \
        : "v"(ha0), "v"(ha1) : "memory")

// Batch-per-XCD LSTM, R18 = R15 (best: 1170us) + poison-revert + sG-delete.
//  * Producer h-stores PLAIN (allocate in L2 = earliest consumer-visible
//    point; R17's sc1 write-through quadrupled HBM traffic, +100% dur).
//  * Poll loads pure sc0; "sc0 sc1" only every 64th retry as a fail-safe.
//  * Operand swap + (hcol,gate) column interleave: compute S^T via
//    mfma(W-frag, h-frag) with bcol = (c&3)*512 + s*16 + wv*4 + (c>>2).
//    D[row=quad*4+r][col=l16] -> lane owns acc[r] = gate r (i,j,f,o) of
//    (hcol=quad, batch=l16&7): gate math fully in-lane, sG relay deleted.
//    A/B fragment per-lane layouts are symmetric -> loaders unchanged.
//  * Certify: v_pk_fma_f16 NaN-poison (sentinel 0x7FC0 is f16-NaN; valid
//    bf16 |h|<=1 halves are finite f16 -> +-0), 4 ILP chains (~40cy).
//  * ds-stage before certify (overlap); 4-chain h-MFMA (dep depth 4).
__global__ __launch_bounds__(256, 1) void k_lstm(const u16* __restrict__ Wt, const u16* __restrict__ Xb,
                                                 u16* __restrict__ hs, const float* __restrict__ bias,
                                                 u32* __restrict__ sync) {
    __shared__ u16 sT[4][4096];        // per-wave 8KB certified h-tile (XOR-swizzled)
    __shared__ int sSlot, sXcc;

    const int tid = threadIdx.x;
    const int lane = tid & 63, wv = tid >> 6;
    const int l16 = lane & 15, quad = lane >> 4;

    // ---- one-time: XCD self-organization (R7/R8-proven; sleep OK here) ----
    if (tid == 0) {
        u32 xcc;
        asm volatile("s_getreg_b32 %0, hwreg(HW_REG_XCC_ID)" : "=s"(xcc));
        xcc &= 7;
        u32 slot = __hip_atomic_fetch_add(sync + xcc * FL, 1u, __ATOMIC_RELAXED, __HIP_MEMORY_SCOPE_AGENT);
        int ok = -1;
        if (slot < 32) {
            int g = 0;
            while (__hip_atomic_load(sync + xcc * FL, __ATOMIC_RELAXED, __HIP_MEMORY_SCOPE_AGENT) < 32u) {
                __builtin_amdgcn_s_sleep(8);
                if (++g > 2000000) { ok = -2; break; }
            }
            if (ok == -1) ok = (int)slot;
        }
        sSlot = ok; sXcc = (int)xcc;
    }
    __syncthreads();
    const int s = sSlot;
    if (s < 0) return;
    const int xcc = sXcc;
    const int b0 = 8 * xcc;

    // this lane's output: hcol = quad (within wave), batch = l16&7 (l16>=8 dup)
    const int hc = s * 16 + wv * 4 + quad;   // global h column
    const float bi = bias[hc];
    const float bj = bias[512 + hc];
    const float bf = bias[1024 + hc] + 1.0f;
    const float bo = bias[1536 + hc];

    // A-operand weight fragments (W^T rows = gate-cols), (hcol,gate)-interleaved:
    // A-row c = l16 -> global col (c&3)*512 + s*16 + wv*4 + (c>>2)
    short8 bfr[20];
    {
        size_t bcol = (size_t)(l16 & 3) * 512 + s * 16 + wv * 4 + (l16 >> 2);
        const u16* wp = Wt + bcol * KDIM + quad * 8;
#pragma unroll
        for (int ks = 0; ks < 20; ++ks) bfr[ks] = *(const short8*)(wp + ks * 32);
    }

    const int bA = l16 & 7;
    float cst = 0.f;
    __syncthreads();

    // x fragments for t=0 (recurrence-independent; 1-step prefetch thereafter)
    short8 xcur[4], xnxt[4];
    {
        const u16* xrow = Xb + ((size_t)b0 + bA) * N_ + quad * 8;
#pragma unroll
        for (int ks = 0; ks < 4; ++ks) xcur[ks] = *(const short8*)(xrow + ks * 32);
    }

    char* wbase = (char*)&sT[wv][0];

    for (int t = 0; t < T_; ++t) {
        // x contribution: independent of h_t, computed before the poll
        floatx4 px = {0.f, 0.f, 0.f, 0.f}, qx = {0.f, 0.f, 0.f, 0.f};
        px = __builtin_amdgcn_mfma_f32_16x16x32_bf16(bfr[16], xcur[0], px, 0, 0, 0);
        qx = __builtin_amdgcn_mfma_f32_16x16x32_bf16(bfr[17], xcur[1], qx, 0, 0, 0);
        px = __builtin_amdgcn_mfma_f32_16x16x32_bf16(bfr[18], xcur[2], px, 0, 0, 0);
        qx = __builtin_amdgcn_mfma_f32_16x16x32_bf16(bfr[19], xcur[3], qx, 0, 0, 0);

        // prefetch next x fragments (completes under the poll latency)
        if (t + 1 < T_) {
            const u16* xrow = Xb + ((size_t)(t + 1) * 64 + b0 + bA) * N_ + quad * 8;
#pragma unroll
            for (int ks = 0; ks < 4; ++ks) xnxt[ks] = *(const short8*)(xrow + ks * 32);
        }

        // ---- certified full-tile poll: 8KB, all 8 rows. ds-stage issues
        //      before certify (overlap); retries just rewrite the region. ----
        u32x4 ch[8];
        {
            u64 ha0 = (u64)(uintptr_t)(hs + ((size_t)t * 64 + b0) * H_ + lane * 8);
            u64 ha1 = ha0 + 4096;
            int g = 0;
            for (;;) {
                if ((g & 63) == 63) { TLOADS("sc0 sc1"); } else { TLOADS("sc0"); }
                // stage to wave-private LDS (XOR swizzle: involution both sides)
#pragma unroll
                for (int j = 0; j < 8; ++j)
                    *(u32x4*)(wbase + j * 1024 + ((lane * 16) ^ (j << 4))) = ch[j];
                // certify: f16 pk-NaN poison, 4 independent chains
                u32 a0 = 0, a1 = 0, a2 = 0, a3 = 0;
#pragma unroll
                for (int c = 0; c < 8; ++c) {
                    asm("v_pk_fma_f16 %0, %1, 0, %0" : "+v"(a0) : "v"(ch[c][0]));
                    asm("v_pk_fma_f16 %0, %1, 0, %0" : "+v"(a1) : "v"(ch[c][1]));
                    asm("v_pk_fma_f16 %0, %1, 0, %0" : "+v"(a2) : "v"(ch[c][2]));
                    asm("v_pk_fma_f16 %0, %1, 0, %0" : "+v"(a3) : "v"(ch[c][3]));
                }
                if (!__any((((a0 | a1) | (a2 | a3)) & 0x7FFF7FFFu) != 0u)) break;
                if (++g > 2000000) break;   // fail-safe: fails LOUDLY (NaN out)
            }
        }

        // ---- B-operand h-fragments from LDS: row bA, u16-col quad*8 + ks*32 ----
        short8 afr[16];
        {
            const char* rb = wbase + bA * 1024;
#pragma unroll
            for (int ks = 0; ks < 16; ++ks)
                afr[ks] = *(const short8*)(rb + ((quad * 16 + ks * 64) ^ (bA << 4)));
        }

        // ---- h-MFMAs: S^T = W-frag x h-frag, 4 independent chains ----
        floatx4 a0 = px, a1 = qx;
        floatx4 a2 = {0.f, 0.f, 0.f, 0.f}, a3 = {0.f, 0.f, 0.f, 0.f};
#pragma unroll
        for (int ks = 0; ks < 16; ks += 4) {
            a0 = __builtin_amdgcn_mfma_f32_16x16x32_bf16(bfr[ks],     afr[ks],     a0, 0, 0, 0);
            a1 = __builtin_amdgcn_mfma_f32_16x16x32_bf16(bfr[ks + 1], afr[ks + 1], a1, 0, 0, 0);
            a2 = __builtin_amdgcn_mfma_f32_16x16x32_bf16(bfr[ks + 2], afr[ks + 2], a2, 0, 0, 0);
            a3 = __builtin_amdgcn_mfma_f32_16x16x32_bf16(bfr[ks + 3], afr[ks + 3], a3, 0, 0, 0);
        }
        floatx4 acc = (a0 + a2) + (a1 + a3);

        // ---- gate math fully in-lane: acc[r] = gate r (i,j,f,o) ----
        cst = sigf(acc[2] + bf) * cst + sigf(acc[0] + bi) * tanh_(acc[1] + bj);
        float h = sigf(acc[3] + bo) * tanh_(cst);

        // one u16 store per lane (l16<8): 4 lanes cover 8 contiguous bytes
        if (l16 < 8)
            hs[((size_t)(t + 1) * 64 + b0 + l16) * H_ + hc] = f2bf(h);

#pragma unroll
        for (int ks = 0; ks < 4; ++ks) xcur[ks] = xnxt[ks];
    }
}

// decoder + loss: rows R = t*64+b of hs[1..512]; 32 rows/block staged in LDS
__global__ __launch_bounds__(256) void k_dec(const u16* __restrict__ hs, const float* __restrict__ Wd,
                                             const float* __restrict__ bd, const float* __restrict__ Y,
                                             float* __restrict__ out) {
    __shared__ u16 sH[32 * H_];
    __shared__ float red[4];
    int tid = threadIdx.x;
    int R0 = blockIdx.x * 32;
    for (int u = tid; u < 2048; u += 256) {
        int row = u >> 6, ch = u & 63;
        *(short8*)(sH + row * H_ + ch * 8) =
            *(const short8*)(hs + (size_t)(64 + R0 + row) * H_ + ch * 8);
    }
    __syncthreads();

    int n = tid & 127, half = tid >> 7;
    float bdv = bd[n];
    float acc[16];
#pragma unroll
    for (int i = 0; i < 16; ++i) acc[i] = 0.f;

    for (int ko = 0; ko < H_ / 8; ++ko) {
        float wv[8];
#pragma unroll
        for (int j = 0; j < 8; ++j) wv[j] = Wd[(ko * 8 + j) * N_ + n];
#pragma unroll
        for (int i = 0; i < 16; ++i) {
            int r = half * 16 + i;
            const uint4 hv = *(const uint4*)(sH + r * H_ + ko * 8);
            acc[i] += __uint_as_float(hv.x << 16) * wv[0] + __uint_as_float(hv.x & 0xFFFF0000u) * wv[1]
                    + __uint_as_float(hv.y << 16) * wv[2] + __uint_as_float(hv.y & 0xFFFF0000u) * wv[3]
                    + __uint_as_float(hv.z << 16) * wv[4] + __uint_as_float(hv.z & 0xFFFF0000u) * wv[5]
                    + __uint_as_float(hv.w << 16) * wv[6] + __uint_as_float(hv.w & 0xFFFF0000u) * wv[7];
        }
    }
    float sse = 0.f;
#pragma unroll
    for (int i = 0; i < 16; ++i) {
        int R = R0 + half * 16 + i;
        int t = R >> 6, b = R & 63;
        float logit = sigf(acc[i] + bdv);
        float d = Y[(size_t)(b * T_ + t) * N_ + n] - logit;
        sse += d * d;
    }
    for (int off = 32; off > 0; off >>= 1) sse += __shfl_down(sse, off, 64);
    if ((tid & 63) == 0) red[tid >> 6] = sse;
    __syncthreads();
    if (tid == 0) {
        float tot = red[0] + red[1] + red[2] + red[3];
        atomicAdd(out, tot * (100.0f / 4194304.0f));
    }
}

extern "C" void kernel_launch(void* const* d_in, const int* in_sizes, int n_in,
                              void* d_out, int out_size, void* d_ws, size_t ws_size,
                              hipStream_t stream) {
    (void)in_sizes; (void)n_in; (void)out_size;
    const float* X  = (const float*)d_in[0];
    const float* Y  = (const float*)d_in[1];
    const float* Wx = (const float*)d_in[2];
    const float* Wh = (const float*)d_in[3];
    const float* bb = (const float*)d_in[4];
    const float* Wd = (const float*)d_in[5];
    const float* bd = (const float*)d_in[6];

    char* ws = (char*)d_ws;
    u32* syncz = (u32*)ws;
    const size_t sync_bytes = 131072;
    u16* hs  = (u16*)(ws + sync_bytes);
    const size_t hs_bytes = (size_t)(T_ + 1) * 64 * H_ * 2;   // 33,619,968
    u16* Xb  = (u16*)(ws + sync_bytes + hs_bytes);
    const size_t xb_bytes = (size_t)T_ * 64 * N_ * 2;         // 8,388,608
    u16* Wt  = (u16*)(ws + sync_bytes + hs_bytes + xb_bytes);
    const size_t need = sync_bytes + hs_bytes + xb_bytes + (size_t)2048 * KDIM * 2;
    if (ws_size < need) return;   // ~44.8 MB scratch required

    (void)hipMemsetAsync(syncz, 0, 65536, stream);            // org counters
    (void)hipMemsetAsync(hs, 0, 64 * H_ * 2, stream);         // h_{-1} = 0 (t=0 rows, NOT NaN)
    (void)hipMemsetAsync(d_out, 0, sizeof(float), stream);

    // NaN-sentinel prefill of hs rows [64, 513*64): 2,097,152 uint4 = 33.5 MB
    k_fill<<<dim3(8192), dim3(256), 0, stream>>>((uint4*)(hs + (size_t)64 * H_));

    k_xb<<<dim3((B_ * T_ * N_) / 256), dim3(256), 0, stream>>>(X, Xb);
    k_wcat<<<dim3((2048 * KDIM) / 256), dim3(256), 0, stream>>>(Wx, Wh, Wt);

    void* args[] = { (void*)&Wt, (void*)&Xb, (void*)&hs, (void*)&bb, (void*)&syncz };
    (void)hipLaunchCooperativeKernel((const void*)k_lstm, dim3(256), dim3(256), args, 0, stream);

    k_dec<<<dim3((B_ * T_) / 32), dim3(256), 0, stream>>>(hs, Wd, bd, Y, (float*)d_out);
}

// Round 10
// 1307.179 us; speedup vs baseline: 8.3883x; 8.3883x over previous
//
#include <hip/hip_runtime.h>
#include <stdint.h>

typedef unsigned short u16;
typedef unsigned int u32;
typedef unsigned long long u64;

#define B_ 64
#define T_ 512
#define N_ 128
#define H_ 512
#define KDIM 640        // H + N
#define FL 32           // u32 per 128B line
// sync lines: [0..7] org counters (agent) only. Consumers poll hs data
// directly against the bf16-NaN sentinel 0x7FC0 (|h|<1 can never produce it).

typedef __attribute__((ext_vector_type(8))) short short8;
typedef __attribute__((ext_vector_type(4))) float floatx4;
typedef __attribute__((ext_vector_type(4))) u32 u32x4;

__device__ __forceinline__ float sigf(float x) { return 1.0f / (1.0f + __expf(-x)); }
__device__ __forceinline__ float tanh_(float x) { return 1.0f - 2.0f / (1.0f + __expf(2.0f * x)); }

__device__ __forceinline__ u16 f2bf(float x) {
    u32 u = __float_as_uint(x);
    u32 r = (u + 0x7FFFu + ((u >> 16) & 1u)) >> 16;   // RNE
    return (u16)r;
}

// X [B,T,N] fp32 -> Xb [T,B,N] bf16
__global__ __launch_bounds__(256) void k_xb(const float* __restrict__ X, u16* __restrict__ Xb) {
    int i = blockIdx.x * 256 + threadIdx.x;
    int n = i & 127, b = (i >> 7) & 63, t = i >> 13;
    Xb[i] = f2bf(X[(b * T_ + t) * N_ + n]);
}

// Wcat^T [2048 cols][640 k] bf16: rows k<512 from Wh, k>=512 from Wx
__global__ __launch_bounds__(256) void k_wcat(const float* __restrict__ Wx, const float* __restrict__ Wh,
                                              u16* __restrict__ Wt) {
    int i = blockIdx.x * 256 + threadIdx.x;
    int c = i & 2047, k = i >> 11;
    float v = (k < H_) ? Wh[k * 2048 + c] : Wx[(k - H_) * 2048 + c];
    Wt[c * KDIM + k] = f2bf(v);
}

// NaN-prefill hs rows [64, 513*64): 0x7FC0 bf16 sentinel.
__global__ __launch_bounds__(256) void k_fill(uint4* __restrict__ p) {
    int i = blockIdx.x * 256 + threadIdx.x;
    uint4 v; v.x = v.y = v.z = v.w = 0x7FC07FC0u;
    p[i] = v;
}

// Full 8KB h-tile load: lane reads 16B from each of the 8 batch rows (row
// stride 1024B; coalesced: 64 lanes cover each 1KB row densely, zero dup).
// ONE asm block so the vmcnt(0) can't be separated from the loads (rule 18).
#define TLOADS(SC) \
    asm volatile( \
        "global_load_dwordx4 %0, %8, off " SC "\n\t" \
        "global_load_dwordx4 %1, %8, off offset:1024 " SC "\n\t" \
        "global_load_dwordx4 %2, %8, off offset:2048 " SC "\n\t" \
        "global_load_dwordx4 %3, %8, off offset:3072 " SC "\n\t" \
        "global_load_dwordx4 %4, %9, off " SC "\n\t" \
        "global_load_dwordx4 %5, %9, off offset:1024 " SC "\n\t" \
        "global_load_dwordx4 %6, %9, off offset:2048 " SC "\n\t" \
        "global_load_dwordx4 %7, %9, off offset:3072 " SC "\n\t" \
        "s_waitcnt vmcnt(0)" \
        : "=&v"(ch[0]), "=&v"(ch[1]), "=&v"(ch[2]), "=&v"(ch[3]), \
          "=&v"(ch[4]), "=&v"(ch[5]), "=&v"(ch[6]), "=&v"(ch[7]) \
        : "v"(ha0), "v"(ha1) : "memory")

// Batch-per-XCD LSTM, R19 = R15 (proven 1170us) + ONLY the sG-delete.
// R18's ~60-round/step spin matched its every-64th "sc0 sc1" hedge cadence:
// plain-sc0 rounds apparently re-hit a stale line until the sc0sc1 round
// refreshes -> the R15 g&1 ALTERNATION is load-bearing and is restored,
// along with R15's integer certify, stage-after-certify, 2-chain MFMA, and
// u32-granularity producer stores (R18's per-lane u16 stores also suspect).
// Kept from R18 (correctness-proven, not implicated): operand swap
// mfma(W-frag, h-frag) with (hcol,gate)-interleaved columns
// (bcol = (c&3)*512 + s*16 + wv*4 + (c>>2)) -> D[row=quad*4+r][col=l16]
// puts gate r of (hcol=quad, batch=l16&7) in-lane: gate math needs no sG
// relay; paired u32 store via shfl_xor(h,16) restores R15's store shape.
// (R20 resubmit: R19 never ran -- the MI355X container failed twice.)
__global__ __launch_bounds__(256, 1) void k_lstm(const u16* __restrict__ Wt, const u16* __restrict__ Xb,
                                                 u16* __restrict__ hs, const float* __restrict__ bias,
                                                 u32* __restrict__ sync) {
    __shared__ u16 sT[4][4096];        // per-wave 8KB certified h-tile (XOR-swizzled)
    __shared__ int sSlot, sXcc;

    const int tid = threadIdx.x;
    const int lane = tid & 63, wv = tid >> 6;
    const int l16 = lane & 15, quad = lane >> 4;

    // ---- one-time: XCD self-organization (R7/R8-proven; sleep OK here) ----
    if (tid == 0) {
        u32 xcc;
        asm volatile("s_getreg_b32 %0, hwreg(HW_REG_XCC_ID)" : "=s"(xcc));
        xcc &= 7;
        u32 slot = __hip_atomic_fetch_add(sync + xcc * FL, 1u, __ATOMIC_RELAXED, __HIP_MEMORY_SCOPE_AGENT);
        int ok = -1;
        if (slot < 32) {
            int g = 0;
            while (__hip_atomic_load(sync + xcc * FL, __ATOMIC_RELAXED, __HIP_MEMORY_SCOPE_AGENT) < 32u) {
                __builtin_amdgcn_s_sleep(8);
                if (++g > 2000000) { ok = -2; break; }
            }
            if (ok == -1) ok = (int)slot;
        }
        sSlot = ok; sXcc = (int)xcc;
    }
    __syncthreads();
    const int s = sSlot;
    if (s < 0) return;
    const int xcc = sXcc;
    const int b0 = 8 * xcc;

    // this lane's output: hcol = quad (within wave), batch = l16&7 (l16>=8 dup)
    const int hc = s * 16 + wv * 4 + quad;   // global h column
    const float bi = bias[hc];
    const float bj = bias[512 + hc];
    const float bf = bias[1024 + hc] + 1.0f;
    const float bo = bias[1536 + hc];

    // A-operand weight fragments (W^T rows), (hcol,gate)-interleaved:
    // A-row c = l16 -> global col (c&3)*512 + s*16 + wv*4 + (c>>2)
    short8 bfr[20];
    {
        size_t bcol = (size_t)(l16 & 3) * 512 + s * 16 + wv * 4 + (l16 >> 2);
        const u16* wp = Wt + bcol * KDIM + quad * 8;
#pragma unroll
        for (int ks = 0; ks < 20; ++ks) bfr[ks] = *(const short8*)(wp + ks * 32);
    }

    const int bA = l16 & 7;
    float cst = 0.f;
    __syncthreads();

    // x fragments for t=0 (recurrence-independent; 1-step prefetch thereafter)
    short8 xcur[4], xnxt[4];
    {
        const u16* xrow = Xb + ((size_t)b0 + bA) * N_ + quad * 8;
#pragma unroll
        for (int ks = 0; ks < 4; ++ks) xcur[ks] = *(const short8*)(xrow + ks * 32);
    }

    char* wbase = (char*)&sT[wv][0];

    for (int t = 0; t < T_; ++t) {
        // x contribution: independent of h_t, computed before the poll
        floatx4 px = {0.f, 0.f, 0.f, 0.f}, qx = {0.f, 0.f, 0.f, 0.f};
        px = __builtin_amdgcn_mfma_f32_16x16x32_bf16(bfr[16], xcur[0], px, 0, 0, 0);
        qx = __builtin_amdgcn_mfma_f32_16x16x32_bf16(bfr[17], xcur[1], qx, 0, 0, 0);
        px = __builtin_amdgcn_mfma_f32_16x16x32_bf16(bfr[18], xcur[2], px, 0, 0, 0);
        qx = __builtin_amdgcn_mfma_f32_16x16x32_bf16(bfr[19], xcur[3], qx, 0, 0, 0);

        // prefetch next x fragments (completes under the poll latency)
        if (t + 1 < T_) {
            const u16* xrow = Xb + ((size_t)(t + 1) * 64 + b0 + bA) * N_ + quad * 8;
#pragma unroll
            for (int ks = 0; ks < 4; ++ks) xnxt[ks] = *(const short8*)(xrow + ks * 32);
        }

        // ---- certified full-tile poll: 8KB, all 8 rows, sentinel bit-check
        //      (R15-exact: alternating sc0 / sc0 sc1, integer ILP check) ----
        u32x4 ch[8];
        {
            u64 ha0 = (u64)(uintptr_t)(hs + ((size_t)t * 64 + b0) * H_ + lane * 8);
            u64 ha1 = ha0 + 4096;
            int g = 0;
            for (;;) {
                if (g & 1) { TLOADS("sc0 sc1"); } else { TLOADS("sc0"); }
                u32 a = 0;
#pragma unroll
                for (int c = 0; c < 8; ++c) {
#pragma unroll
                    for (int k = 0; k < 4; ++k) {
                        u32 tt = ch[c][k] ^ 0x7FC07FC0u;
                        a |= ((tt - 0x00010001u) & ~tt);
                    }
                }
                if (!__any((a & 0x80008000u) != 0u)) break;
                if (++g > 2000000) break;   // fail-safe: fails LOUDLY (NaN out)
            }
        }

        // ---- stage to wave-private LDS (XOR swizzle: involution both sides) ----
#pragma unroll
        for (int j = 0; j < 8; ++j)
            *(u32x4*)(wbase + j * 1024 + ((lane * 16) ^ (j << 4))) = ch[j];

        // ---- B-operand h-fragments from LDS: row bA, u16-col quad*8 + ks*32 ----
        short8 afr[16];
        {
            const char* rb = wbase + bA * 1024;
#pragma unroll
            for (int ks = 0; ks < 16; ++ks)
                afr[ks] = *(const short8*)(rb + ((quad * 16 + ks * 64) ^ (bA << 4)));
        }

        // ---- h-MFMAs: S^T = W-frag x h-frag, 2 chains (R15-exact depth) ----
        floatx4 p = px, q = qx;
#pragma unroll
        for (int ks = 0; ks < 16; ks += 2) {
            p = __builtin_amdgcn_mfma_f32_16x16x32_bf16(bfr[ks],     afr[ks],     p, 0, 0, 0);
            q = __builtin_amdgcn_mfma_f32_16x16x32_bf16(bfr[ks + 1], afr[ks + 1], q, 0, 0, 0);
        }
        floatx4 acc = p + q;

        // ---- gate math fully in-lane: acc[r] = gate r (i,j,f,o) ----
        cst = sigf(acc[2] + bf) * cst + sigf(acc[0] + bi) * tanh_(acc[1] + bj);
        float h = sigf(acc[3] + bo) * tanh_(cst);

        // pack across quad pairs (cols quad, quad^1) -> u32 store, R15 shape:
        // per row two u32 at cols wv*4+{0,2} (8B contiguous), 16 active lanes
        float hq = __shfl_xor(h, 16, 64);
        if ((quad & 1) == 0 && l16 < 8) {
            u32 pk = ((u32)f2bf(hq) << 16) | (u32)f2bf(h);
            *(u32*)(hs + ((size_t)(t + 1) * 64 + b0 + l16) * H_ + hc) = pk;
        }

#pragma unroll
        for (int ks = 0; ks < 4; ++ks) xcur[ks] = xnxt[ks];
    }
}

// decoder + loss: rows R = t*64+b of hs[1..512]; 32 rows/block staged in LDS
__global__ __launch_bounds__(256) void k_dec(const u16* __restrict__ hs, const float* __restrict__ Wd,
                                             const float* __restrict__ bd, const float* __restrict__ Y,
                                             float* __restrict__ out) {
    __shared__ u16 sH[32 * H_];
    __shared__ float red[4];
    int tid = threadIdx.x;
    int R0 = blockIdx.x * 32;
    for (int u = tid; u < 2048; u += 256) {
        int row = u >> 6, ch = u & 63;
        *(short8*)(sH + row * H_ + ch * 8) =
            *(const short8*)(hs + (size_t)(64 + R0 + row) * H_ + ch * 8);
    }
    __syncthreads();

    int n = tid & 127, half = tid >> 7;
    float bdv = bd[n];
    float acc[16];
#pragma unroll
    for (int i = 0; i < 16; ++i) acc[i] = 0.f;

    for (int ko = 0; ko < H_ / 8; ++ko) {
        float wv[8];
#pragma unroll
        for (int j = 0; j < 8; ++j) wv[j] = Wd[(ko * 8 + j) * N_ + n];
#pragma unroll
        for (int i = 0; i < 16; ++i) {
            int r = half * 16 + i;
            const uint4 hv = *(const uint4*)(sH + r * H_ + ko * 8);
            acc[i] += __uint_as_float(hv.x << 16) * wv[0] + __uint_as_float(hv.x & 0xFFFF0000u) * wv[1]
                    + __uint_as_float(hv.y << 16) * wv[2] + __uint_as_float(hv.y & 0xFFFF0000u) * wv[3]
                    + __uint_as_float(hv.z << 16) * wv[4] + __uint_as_float(hv.z & 0xFFFF0000u) * wv[5]
                    + __uint_as_float(hv.w << 16) * wv[6] + __uint_as_float(hv.w & 0xFFFF0000u) * wv[7];
        }
    }
    float sse = 0.f;
#pragma unroll
    for (int i = 0; i < 16; ++i) {
        int R = R0 + half * 16 + i;
        int t = R >> 6, b = R & 63;
        float logit = sigf(acc[i] + bdv);
        float d = Y[(size_t)(b * T_ + t) * N_ + n] - logit;
        sse += d * d;
    }
    for (int off = 32; off > 0; off >>= 1) sse += __shfl_down(sse, off, 64);
    if ((tid & 63) == 0) red[tid >> 6] = sse;
    __syncthreads();
    if (tid == 0) {
        float tot = red[0] + red[1] + red[2] + red[3];
        atomicAdd(out, tot * (100.0f / 4194304.0f));
    }
}

extern "C" void kernel_launch(void* const* d_in, const int* in_sizes, int n_in,
                              void* d_out, int out_size, void* d_ws, size_t ws_size,
                              hipStream_t stream) {
    (void)in_sizes; (void)n_in; (void)out_size;
    const float* X  = (const float*)d_in[0];
    const float* Y  = (const float*)d_in[1];
    const float* Wx = (const float*)d_in[2];
    const float* Wh = (const float*)d_in[3];
    const float* bb = (const float*)d_in[4];
    const float* Wd = (const float*)d_in[5];
    const float* bd = (const float*)d_in[6];

    char* ws = (char*)d_ws;
    u32* syncz = (u32*)ws;
    const size_t sync_bytes = 131072;
    u16* hs  = (u16*)(ws + sync_bytes);
    const size_t hs_bytes = (size_t)(T_ + 1) * 64 * H_ * 2;   // 33,619,968
    u16* Xb  = (u16*)(ws + sync_bytes + hs_bytes);
    const size_t xb_bytes = (size_t)T_ * 64 * N_ * 2;         // 8,388,608
    u16* Wt  = (u16*)(ws + sync_bytes + hs_bytes + xb_bytes);
    const size_t need = sync_bytes + hs_bytes + xb_bytes + (size_t)2048 * KDIM * 2;
    if (ws_size < need) return;   // ~44.8 MB scratch required

    (void)hipMemsetAsync(syncz, 0, 65536, stream);            // org counters
    (void)hipMemsetAsync(hs, 0, 64 * H_ * 2, stream);         // h_{-1} = 0 (t=0 rows, NOT NaN)
    (void)hipMemsetAsync(d_out, 0, sizeof(float), stream);

    // NaN-sentinel prefill of hs rows [64, 513*64): 2,097,152 uint4 = 33.5 MB
    k_fill<<<dim3(8192), dim3(256), 0, stream>>>((uint4*)(hs + (size_t)64 * H_));

    k_xb<<<dim3((B_ * T_ * N_) / 256), dim3(256), 0, stream>>>(X, Xb);
    k_wcat<<<dim3((2048 * KDIM) / 256), dim3(256), 0, stream>>>(Wx, Wh, Wt);

    void* args[] = { (void*)&Wt, (void*)&Xb, (void*)&hs, (void*)&bb, (void*)&syncz };
    (void)hipLaunchCooperativeKernel((const void*)k_lstm, dim3(256), dim3(256), args, 0, stream);

    k_dec<<<dim3((B_ * T_) / 32), dim3(256), 0, stream>>>(hs, Wd, bd, Y, (float*)d_out);
}

// Round 11
// 1190.339 us; speedup vs baseline: 9.2117x; 1.0982x over previous
//
#include <hip/hip_runtime.h>
#include <stdint.h>

typedef unsigned short u16;
typedef unsigned int u32;
typedef unsigned long long u64;

#define B_ 64
#define T_ 512
#define N_ 128
#define H_ 512
#define KDIM 640        // H + N
#define FL 32           // u32 per 128B line
// sync lines: [0..7] org counters (agent) only. Consumers poll hs data
// directly against the bf16-NaN sentinel 0x7FC0 (|h|<1 can never produce it).

typedef __attribute__((ext_vector_type(8))) short short8;
typedef __attribute__((ext_vector_type(4))) float floatx4;
typedef __attribute__((ext_vector_type(4))) u32 u32x4;

__device__ __forceinline__ float sigf(float x) { return 1.0f / (1.0f + __expf(-x)); }
__device__ __forceinline__ float tanh_(float x) { return 1.0f - 2.0f / (1.0f + __expf(2.0f * x)); }

__device__ __forceinline__ u16 f2bf(float x) {
    u32 u = __float_as_uint(x);
    u32 r = (u + 0x7FFFu + ((u >> 16) & 1u)) >> 16;   // RNE
    return (u16)r;
}

// X [B,T,N] fp32 -> Xb [T,B,N] bf16
__global__ __launch_bounds__(256) void k_xb(const float* __restrict__ X, u16* __restrict__ Xb) {
    int i = blockIdx.x * 256 + threadIdx.x;
    int n = i & 127, b = (i >> 7) & 63, t = i >> 13;
    Xb[i] = f2bf(X[(b * T_ + t) * N_ + n]);
}

// Wcat^T [2048 cols][640 k] bf16: rows k<512 from Wh, k>=512 from Wx
__global__ __launch_bounds__(256) void k_wcat(const float* __restrict__ Wx, const float* __restrict__ Wh,
                                              u16* __restrict__ Wt) {
    int i = blockIdx.x * 256 + threadIdx.x;
    int c = i & 2047, k = i >> 11;
    float v = (k < H_) ? Wh[k * 2048 + c] : Wx[(k - H_) * 2048 + c];
    Wt[c * KDIM + k] = f2bf(v);
}

// NaN-prefill hs rows [64, 513*64): 0x7FC0 bf16 sentinel.
__global__ __launch_bounds__(256) void k_fill(uint4* __restrict__ p) {
    int i = blockIdx.x * 256 + threadIdx.x;
    uint4 v; v.x = v.y = v.z = v.w = 0x7FC07FC0u;
    p[i] = v;
}

// Full 8KB h-tile load: lane reads 16B from each of the 8 batch rows (row
// stride 1024B; coalesced: 64 lanes cover each 1KB row densely, zero dup).
// ONE asm block so the vmcnt(0) can't be separated from the loads (rule 18).
#define TLOADS(SC) \
    asm volatile( \
        "global_load_dwordx4 %0, %8, off " SC "\n\t" \
        "global_load_dwordx4 %1, %8, off offset:1024 " SC "\n\t" \
        "global_load_dwordx4 %2, %8, off offset:2048 " SC "\n\t" \
        "global_load_dwordx4 %3, %8, off offset:3072 " SC "\n\t" \
        "global_load_dwordx4 %4, %9, off " SC "\n\t" \
        "global_load_dwordx4 %5, %9, off offset:1024 " SC "\n\t" \
        "global_load_dwordx4 %6, %9, off offset:2048 " SC "\n\t" \
        "global_load_dwordx4 %7, %9, off offset:3072 " SC "\n\t" \
        "s_waitcnt vmcnt(0)" \
        : "=&v"(ch[0]), "=&v"(ch[1]), "=&v"(ch[2]), "=&v"(ch[3]), \
          "=&v"(ch[4]), "=&v"(ch[5]), "=&v"(ch[6]), "=&v"(ch[7]) \
        : "v"(ha0), "v"(ha1) : "memory")

// Batch-per-XCD LSTM, R21 = R20 (proven 1157us) + single-certifier.
// R20's residual 2.26us/step closes arithmetically as L2 poll contention:
// ALL 4 waves of all 32 blocks polled the full 8KB tile -> 1MB/XCD/round
// (~250ns at per-XCD L2 BW) x ~9 round-equivalents = 2.26us. (R13 already
// proved single-poller was worth 250us on the old structure; R15 silently
// reintroduced 4x polling.) Now ONLY wave 0 polls+certifies (R15-exact
// TLOADS, g&1 sc0/sc0sc1 hedge, integer certify), stages the tile into a
// SHARED double-buffered LDS tile sT[t&1], release-stores an LDS epoch;
// waves 1-3 spin on the epoch (zero L2 traffic) and ds_read fragments from
// the shared tile. Double-buffer race-freedom: wave0 staging step u implies
// all XCD waves stored h_u => every sibling completed step u-1 => its reads
// of buf[(u-2)&1]=buf[u&1] are done. Everything else R20-verbatim.
__global__ __launch_bounds__(256, 1) void k_lstm(const u16* __restrict__ Wt, const u16* __restrict__ Xb,
                                                 u16* __restrict__ hs, const float* __restrict__ bias,
                                                 u32* __restrict__ sync) {
    __shared__ u16 sT[2][4096];        // shared 2 x 8KB certified h-tile (XOR-swizzled)
    __shared__ int sSlot, sXcc, sEpoch;

    const int tid = threadIdx.x;
    const int lane = tid & 63, wv = tid >> 6;
    const int l16 = lane & 15, quad = lane >> 4;

    // ---- one-time: XCD self-organization (R7/R8-proven; sleep OK here) ----
    if (tid == 0) {
        u32 xcc;
        asm volatile("s_getreg_b32 %0, hwreg(HW_REG_XCC_ID)" : "=s"(xcc));
        xcc &= 7;
        u32 slot = __hip_atomic_fetch_add(sync + xcc * FL, 1u, __ATOMIC_RELAXED, __HIP_MEMORY_SCOPE_AGENT);
        int ok = -1;
        if (slot < 32) {
            int g = 0;
            while (__hip_atomic_load(sync + xcc * FL, __ATOMIC_RELAXED, __HIP_MEMORY_SCOPE_AGENT) < 32u) {
                __builtin_amdgcn_s_sleep(8);
                if (++g > 2000000) { ok = -2; break; }
            }
            if (ok == -1) ok = (int)slot;
        }
        sSlot = ok; sXcc = (int)xcc; sEpoch = -1;
    }
    __syncthreads();
    const int s = sSlot;
    if (s < 0) return;
    const int xcc = sXcc;
    const int b0 = 8 * xcc;

    // this lane's output: hcol = quad (within wave), batch = l16&7 (l16>=8 dup)
    const int hc = s * 16 + wv * 4 + quad;   // global h column
    const float bi = bias[hc];
    const float bj = bias[512 + hc];
    const float bf = bias[1024 + hc] + 1.0f;
    const float bo = bias[1536 + hc];

    // A-operand weight fragments (W^T rows), (hcol,gate)-interleaved:
    // A-row c = l16 -> global col (c&3)*512 + s*16 + wv*4 + (c>>2)
    short8 bfr[20];
    {
        size_t bcol = (size_t)(l16 & 3) * 512 + s * 16 + wv * 4 + (l16 >> 2);
        const u16* wp = Wt + bcol * KDIM + quad * 8;
#pragma unroll
        for (int ks = 0; ks < 20; ++ks) bfr[ks] = *(const short8*)(wp + ks * 32);
    }

    const int bA = l16 & 7;
    float cst = 0.f;
    __syncthreads();

    // x fragments for t=0 (recurrence-independent; 1-step prefetch thereafter)
    short8 xcur[4], xnxt[4];
    {
        const u16* xrow = Xb + ((size_t)b0 + bA) * N_ + quad * 8;
#pragma unroll
        for (int ks = 0; ks < 4; ++ks) xcur[ks] = *(const short8*)(xrow + ks * 32);
    }

    for (int t = 0; t < T_; ++t) {
        char* tb = (char*)&sT[t & 1][0];

        // x contribution: independent of h_t, computed before the wait
        floatx4 px = {0.f, 0.f, 0.f, 0.f}, qx = {0.f, 0.f, 0.f, 0.f};
        px = __builtin_amdgcn_mfma_f32_16x16x32_bf16(bfr[16], xcur[0], px, 0, 0, 0);
        qx = __builtin_amdgcn_mfma_f32_16x16x32_bf16(bfr[17], xcur[1], qx, 0, 0, 0);
        px = __builtin_amdgcn_mfma_f32_16x16x32_bf16(bfr[18], xcur[2], px, 0, 0, 0);
        qx = __builtin_amdgcn_mfma_f32_16x16x32_bf16(bfr[19], xcur[3], qx, 0, 0, 0);

        // prefetch next x fragments (completes under the wait latency)
        if (t + 1 < T_) {
            const u16* xrow = Xb + ((size_t)(t + 1) * 64 + b0 + bA) * N_ + quad * 8;
#pragma unroll
            for (int ks = 0; ks < 4; ++ks) xnxt[ks] = *(const short8*)(xrow + ks * 32);
        }

        if (wv == 0) {
            // ---- single certifier: full-tile poll (R15-exact rounds) ----
            u32x4 ch[8];
            u64 ha0 = (u64)(uintptr_t)(hs + ((size_t)t * 64 + b0) * H_ + lane * 8);
            u64 ha1 = ha0 + 4096;
            int g = 0;
            for (;;) {
                if (g & 1) { TLOADS("sc0 sc1"); } else { TLOADS("sc0"); }
                u32 a = 0;
#pragma unroll
                for (int c = 0; c < 8; ++c) {
#pragma unroll
                    for (int k = 0; k < 4; ++k) {
                        u32 tt = ch[c][k] ^ 0x7FC07FC0u;
                        a |= ((tt - 0x00010001u) & ~tt);
                    }
                }
                if (!__any((a & 0x80008000u) != 0u)) break;
                if (++g > 2000000) break;   // fail-safe: fails LOUDLY (NaN out)
            }
            // stage certified tile to shared buf (XOR swizzle, involution)
#pragma unroll
            for (int j = 0; j < 8; ++j)
                *(u32x4*)(tb + j * 1024 + ((lane * 16) ^ (j << 4))) = ch[j];
            // publish epoch: drain ds_writes, then release-store
            asm volatile("s_waitcnt lgkmcnt(0)" ::: "memory");
            __hip_atomic_store(&sEpoch, t, __ATOMIC_RELEASE, __HIP_MEMORY_SCOPE_WORKGROUP);
        } else {
            // waves 1-3: zero-L2 LDS epoch spin
            int g = 0;
            while (__hip_atomic_load(&sEpoch, __ATOMIC_ACQUIRE, __HIP_MEMORY_SCOPE_WORKGROUP) < t) {
                if (++g > 100000000) break;   // fail-safe
            }
        }

        // ---- B-operand h-fragments from shared LDS: row bA, col quad*8+ks*32 ----
        short8 afr[16];
        {
            const char* rb = tb + bA * 1024;
#pragma unroll
            for (int ks = 0; ks < 16; ++ks)
                afr[ks] = *(const short8*)(rb + ((quad * 16 + ks * 64) ^ (bA << 4)));
        }

        // ---- h-MFMAs: S^T = W-frag x h-frag, 2 chains (proven depth) ----
        floatx4 p = px, q = qx;
#pragma unroll
        for (int ks = 0; ks < 16; ks += 2) {
            p = __builtin_amdgcn_mfma_f32_16x16x32_bf16(bfr[ks],     afr[ks],     p, 0, 0, 0);
            q = __builtin_amdgcn_mfma_f32_16x16x32_bf16(bfr[ks + 1], afr[ks + 1], q, 0, 0, 0);
        }
        floatx4 acc = p + q;

        // ---- gate math fully in-lane: acc[r] = gate r (i,j,f,o) ----
        cst = sigf(acc[2] + bf) * cst + sigf(acc[0] + bi) * tanh_(acc[1] + bj);
        float h = sigf(acc[3] + bo) * tanh_(cst);

        // pack across quad pairs (cols quad, quad^1) -> u32 store:
        // per row two u32 at cols wv*4+{0,2} (8B contiguous), 16 active lanes
        float hq = __shfl_xor(h, 16, 64);
        if ((quad & 1) == 0 && l16 < 8) {
            u32 pk = ((u32)f2bf(hq) << 16) | (u32)f2bf(h);
            *(u32*)(hs + ((size_t)(t + 1) * 64 + b0 + l16) * H_ + hc) = pk;
        }

#pragma unroll
        for (int ks = 0; ks < 4; ++ks) xcur[ks] = xnxt[ks];
    }
}

// decoder + loss: rows R = t*64+b of hs[1..512]; 32 rows/block staged in LDS
__global__ __launch_bounds__(256) void k_dec(const u16* __restrict__ hs, const float* __restrict__ Wd,
                                             const float* __restrict__ bd, const float* __restrict__ Y,
                                             float* __restrict__ out) {
    __shared__ u16 sH[32 * H_];
    __shared__ float red[4];
    int tid = threadIdx.x;
    int R0 = blockIdx.x * 32;
    for (int u = tid; u < 2048; u += 256) {
        int row = u >> 6, ch = u & 63;
        *(short8*)(sH + row * H_ + ch * 8) =
            *(const short8*)(hs + (size_t)(64 + R0 + row) * H_ + ch * 8);
    }
    __syncthreads();

    int n = tid & 127, half = tid >> 7;
    float bdv = bd[n];
    float acc[16];
#pragma unroll
    for (int i = 0; i < 16; ++i) acc[i] = 0.f;

    for (int ko = 0; ko < H_ / 8; ++ko) {
        float wv[8];
#pragma unroll
        for (int j = 0; j < 8; ++j) wv[j] = Wd[(ko * 8 + j) * N_ + n];
#pragma unroll
        for (int i = 0; i < 16; ++i) {
            int r = half * 16 + i;
            const uint4 hv = *(const uint4*)(sH + r * H_ + ko * 8);
            acc[i] += __uint_as_float(hv.x << 16) * wv[0] + __uint_as_float(hv.x & 0xFFFF0000u) * wv[1]
                    + __uint_as_float(hv.y << 16) * wv[2] + __uint_as_float(hv.y & 0xFFFF0000u) * wv[3]
                    + __uint_as_float(hv.z << 16) * wv[4] + __uint_as_float(hv.z & 0xFFFF0000u) * wv[5]
                    + __uint_as_float(hv.w << 16) * wv[6] + __uint_as_float(hv.w & 0xFFFF0000u) * wv[7];
        }
    }
    float sse = 0.f;
#pragma unroll
    for (int i = 0; i < 16; ++i) {
        int R = R0 + half * 16 + i;
        int t = R >> 6, b = R & 63;
        float logit = sigf(acc[i] + bdv);
        float d = Y[(size_t)(b * T_ + t) * N_ + n] - logit;
        sse += d * d;
    }
    for (int off = 32; off > 0; off >>= 1) sse += __shfl_down(sse, off, 64);
    if ((tid & 63) == 0) red[tid >> 6] = sse;
    __syncthreads();
    if (tid == 0) {
        float tot = red[0] + red[1] + red[2] + red[3];
        atomicAdd(out, tot * (100.0f / 4194304.0f));
    }
}

extern "C" void kernel_launch(void* const* d_in, const int* in_sizes, int n_in,
                              void* d_out, int out_size, void* d_ws, size_t ws_size,
                              hipStream_t stream) {
    (void)in_sizes; (void)n_in; (void)out_size;
    const float* X  = (const float*)d_in[0];
    const float* Y  = (const float*)d_in[1];
    const float* Wx = (const float*)d_in[2];
    const float* Wh = (const float*)d_in[3];
    const float* bb = (const float*)d_in[4];
    const float* Wd = (const float*)d_in[5];
    const float* bd = (const float*)d_in[6];

    char* ws = (char*)d_ws;
    u32* syncz = (u32*)ws;
    const size_t sync_bytes = 131072;
    u16* hs  = (u16*)(ws + sync_bytes);
    const size_t hs_bytes = (size_t)(T_ + 1) * 64 * H_ * 2;   // 33,619,968
    u16* Xb  = (u16*)(ws + sync_bytes + hs_bytes);
    const size_t xb_bytes = (size_t)T_ * 64 * N_ * 2;         // 8,388,608
    u16* Wt  = (u16*)(ws + sync_bytes + hs_bytes + xb_bytes);
    const size_t need = sync_bytes + hs_bytes + xb_bytes + (size_t)2048 * KDIM * 2;
    if (ws_size < need) return;   // ~44.8 MB scratch required

    (void)hipMemsetAsync(syncz, 0, 65536, stream);            // org counters
    (void)hipMemsetAsync(hs, 0, 64 * H_ * 2, stream);         // h_{-1} = 0 (t=0 rows, NOT NaN)
    (void)hipMemsetAsync(d_out, 0, sizeof(float), stream);

    // NaN-sentinel prefill of hs rows [64, 513*64): 2,097,152 uint4 = 33.5 MB
    k_fill<<<dim3(8192), dim3(256), 0, stream>>>((uint4*)(hs + (size_t)64 * H_));

    k_xb<<<dim3((B_ * T_ * N_) / 256), dim3(256), 0, stream>>>(X, Xb);
    k_wcat<<<dim3((2048 * KDIM) / 256), dim3(256), 0, stream>>>(Wx, Wh, Wt);

    void* args[] = { (void*)&Wt, (void*)&Xb, (void*)&hs, (void*)&bb, (void*)&syncz };
    (void)hipLaunchCooperativeKernel((const void*)k_lstm, dim3(256), dim3(256), args, 0, stream);

    k_dec<<<dim3((B_ * T_) / 32), dim3(256), 0, stream>>>(hs, Wd, bd, Y, (float*)d_out);
}

// Round 12
// 1170.854 us; speedup vs baseline: 9.3650x; 1.0166x over previous
//
#include <hip/hip_runtime.h>
#include <stdint.h>

typedef unsigned short u16;
typedef unsigned int u32;
typedef unsigned long long u64;

#define B_ 64
#define T_ 512
#define N_ 128
#define H_ 512
#define KDIM 640        // H + N
#define FL 32           // u32 per 128B line
// sync lines: [0..7] org counters (agent) only. Consumers poll hs data
// directly against the bf16-NaN sentinel 0x7FC0 (|h|<1 can never produce it).

typedef __attribute__((ext_vector_type(8))) short short8;
typedef __attribute__((ext_vector_type(4))) float floatx4;
typedef __attribute__((ext_vector_type(4))) u32 u32x4;

__device__ __forceinline__ float sigf(float x) { return 1.0f / (1.0f + __expf(-x)); }
__device__ __forceinline__ float tanh_(float x) { return 1.0f - 2.0f / (1.0f + __expf(2.0f * x)); }

__device__ __forceinline__ u16 f2bf(float x) {
    u32 u = __float_as_uint(x);
    u32 r = (u + 0x7FFFu + ((u >> 16) & 1u)) >> 16;   // RNE
    return (u16)r;
}

// X [B,T,N] fp32 -> Xb [T,B,N] bf16
__global__ __launch_bounds__(256) void k_xb(const float* __restrict__ X, u16* __restrict__ Xb) {
    int i = blockIdx.x * 256 + threadIdx.x;
    int n = i & 127, b = (i >> 7) & 63, t = i >> 13;
    Xb[i] = f2bf(X[(b * T_ + t) * N_ + n]);
}

// Wcat^T [2048 cols][640 k] bf16: rows k<512 from Wh, k>=512 from Wx
__global__ __launch_bounds__(256) void k_wcat(const float* __restrict__ Wx, const float* __restrict__ Wh,
                                              u16* __restrict__ Wt) {
    int i = blockIdx.x * 256 + threadIdx.x;
    int c = i & 2047, k = i >> 11;
    float v = (k < H_) ? Wh[k * 2048 + c] : Wx[(k - H_) * 2048 + c];
    Wt[c * KDIM + k] = f2bf(v);
}

// NaN-prefill hs rows [64, 513*64): 0x7FC0 bf16 sentinel.
__global__ __launch_bounds__(256) void k_fill(uint4* __restrict__ p) {
    int i = blockIdx.x * 256 + threadIdx.x;
    uint4 v; v.x = v.y = v.z = v.w = 0x7FC07FC0u;
    p[i] = v;
}

// Full 8KB h-tile load: lane reads 16B from each of the 8 batch rows (row
// stride 1024B; coalesced: 64 lanes cover each 1KB row densely, zero dup).
// ONE asm block so the vmcnt(0) can't be separated from the loads (rule 18).
#define TLOADS(SC) \
    asm volatile( \
        "global_load_dwordx4 %0, %8, off " SC "\n\t" \
        "global_load_dwordx4 %1, %8, off offset:1024 " SC "\n\t" \
        "global_load_dwordx4 %2, %8, off offset:2048 " SC "\n\t" \
        "global_load_dwordx4 %3, %8, off offset:3072 " SC "\n\t" \
        "global_load_dwordx4 %4, %9, off " SC "\n\t" \
        "global_load_dwordx4 %5, %9, off offset:1024 " SC "\n\t" \
        "global_load_dwordx4 %6, %9, off offset:2048 " SC "\n\t" \
        "global_load_dwordx4 %7, %9, off offset:3072 " SC "\n\t" \
        "s_waitcnt vmcnt(0)" \
        : "=&v"(ch[0]), "=&v"(ch[1]), "=&v"(ch[2]), "=&v"(ch[3]), \
          "=&v"(ch[4]), "=&v"(ch[5]), "=&v"(ch[6]), "=&v"(ch[7]) \
        : "v"(ha0), "v"(ha1) : "memory")

// Batch-per-XCD LSTM, R22 = R21 (proven 984us) + certify-path deltas:
//  (1) ALL poll rounds "sc0 sc1". R18's forensic signature (spin count ~60
//      matching its every-64th sc0sc1 cadence) says plain-sc0 rounds re-hit
//      a stale L1 line and never converge -- only sc0sc1 rounds actually
//      observe L2. R21's alternation thus wasted every other round; detect
//      cadence should halve. R21's FETCH arithmetic (~4.8KB/step/XCD = just
//      producer write-allocate) shows sc0sc1 LOADS are L2-serviced, so no
//      HBM cost (unlike R17's store-side sc1, which counters convicted).
//      Discriminator: if FETCH_SIZE jumps, this theory is wrong -> revert.
//  (2) stage-inside-poll-loop (R17's overlap): ds_writes issue every round
//      before the certify ALU -> final round's staging is done at detect;
//      removes ~60-80cy of post-detect serialization. Retries just
//      overwrite the buffer (waves 1-3 are epoch-gated; no race).
__global__ __launch_bounds__(256, 1) void k_lstm(const u16* __restrict__ Wt, const u16* __restrict__ Xb,
                                                 u16* __restrict__ hs, const float* __restrict__ bias,
                                                 u32* __restrict__ sync) {
    __shared__ u16 sT[2][4096];        // shared 2 x 8KB certified h-tile (XOR-swizzled)
    __shared__ int sSlot, sXcc, sEpoch;

    const int tid = threadIdx.x;
    const int lane = tid & 63, wv = tid >> 6;
    const int l16 = lane & 15, quad = lane >> 4;

    // ---- one-time: XCD self-organization (R7/R8-proven; sleep OK here) ----
    if (tid == 0) {
        u32 xcc;
        asm volatile("s_getreg_b32 %0, hwreg(HW_REG_XCC_ID)" : "=s"(xcc));
        xcc &= 7;
        u32 slot = __hip_atomic_fetch_add(sync + xcc * FL, 1u, __ATOMIC_RELAXED, __HIP_MEMORY_SCOPE_AGENT);
        int ok = -1;
        if (slot < 32) {
            int g = 0;
            while (__hip_atomic_load(sync + xcc * FL, __ATOMIC_RELAXED, __HIP_MEMORY_SCOPE_AGENT) < 32u) {
                __builtin_amdgcn_s_sleep(8);
                if (++g > 2000000) { ok = -2; break; }
            }
            if (ok == -1) ok = (int)slot;
        }
        sSlot = ok; sXcc = (int)xcc; sEpoch = -1;
    }
    __syncthreads();
    const int s = sSlot;
    if (s < 0) return;
    const int xcc = sXcc;
    const int b0 = 8 * xcc;

    // this lane's output: hcol = quad (within wave), batch = l16&7 (l16>=8 dup)
    const int hc = s * 16 + wv * 4 + quad;   // global h column
    const float bi = bias[hc];
    const float bj = bias[512 + hc];
    const float bf = bias[1024 + hc] + 1.0f;
    const float bo = bias[1536 + hc];

    // A-operand weight fragments (W^T rows), (hcol,gate)-interleaved:
    // A-row c = l16 -> global col (c&3)*512 + s*16 + wv*4 + (c>>2)
    short8 bfr[20];
    {
        size_t bcol = (size_t)(l16 & 3) * 512 + s * 16 + wv * 4 + (l16 >> 2);
        const u16* wp = Wt + bcol * KDIM + quad * 8;
#pragma unroll
        for (int ks = 0; ks < 20; ++ks) bfr[ks] = *(const short8*)(wp + ks * 32);
    }

    const int bA = l16 & 7;
    float cst = 0.f;
    __syncthreads();

    // x fragments for t=0 (recurrence-independent; 1-step prefetch thereafter)
    short8 xcur[4], xnxt[4];
    {
        const u16* xrow = Xb + ((size_t)b0 + bA) * N_ + quad * 8;
#pragma unroll
        for (int ks = 0; ks < 4; ++ks) xcur[ks] = *(const short8*)(xrow + ks * 32);
    }

    for (int t = 0; t < T_; ++t) {
        char* tb = (char*)&sT[t & 1][0];

        // x contribution: independent of h_t, computed before the wait
        floatx4 px = {0.f, 0.f, 0.f, 0.f}, qx = {0.f, 0.f, 0.f, 0.f};
        px = __builtin_amdgcn_mfma_f32_16x16x32_bf16(bfr[16], xcur[0], px, 0, 0, 0);
        qx = __builtin_amdgcn_mfma_f32_16x16x32_bf16(bfr[17], xcur[1], qx, 0, 0, 0);
        px = __builtin_amdgcn_mfma_f32_16x16x32_bf16(bfr[18], xcur[2], px, 0, 0, 0);
        qx = __builtin_amdgcn_mfma_f32_16x16x32_bf16(bfr[19], xcur[3], qx, 0, 0, 0);

        // prefetch next x fragments (completes under the wait latency)
        if (t + 1 < T_) {
            const u16* xrow = Xb + ((size_t)(t + 1) * 64 + b0 + bA) * N_ + quad * 8;
#pragma unroll
            for (int ks = 0; ks < 4; ++ks) xnxt[ks] = *(const short8*)(xrow + ks * 32);
        }

        if (wv == 0) {
            // ---- single certifier: full-tile poll, every round effective ----
            u32x4 ch[8];
            u64 ha0 = (u64)(uintptr_t)(hs + ((size_t)t * 64 + b0) * H_ + lane * 8);
            u64 ha1 = ha0 + 4096;
            int g = 0;
            for (;;) {
                TLOADS("sc0 sc1");
                // speculative stage (overlaps certify ALU; retry overwrites)
#pragma unroll
                for (int j = 0; j < 8; ++j)
                    *(u32x4*)(tb + j * 1024 + ((lane * 16) ^ (j << 4))) = ch[j];
                u32 a = 0;
#pragma unroll
                for (int c = 0; c < 8; ++c) {
#pragma unroll
                    for (int k = 0; k < 4; ++k) {
                        u32 tt = ch[c][k] ^ 0x7FC07FC0u;
                        a |= ((tt - 0x00010001u) & ~tt);
                    }
                }
                if (!__any((a & 0x80008000u) != 0u)) break;
                if (++g > 2000000) break;   // fail-safe: fails LOUDLY (NaN out)
            }
            // publish epoch: drain ds_writes, then release-store
            asm volatile("s_waitcnt lgkmcnt(0)" ::: "memory");
            __hip_atomic_store(&sEpoch, t, __ATOMIC_RELEASE, __HIP_MEMORY_SCOPE_WORKGROUP);
        } else {
            // waves 1-3: zero-L2 LDS epoch spin
            int g = 0;
            while (__hip_atomic_load(&sEpoch, __ATOMIC_ACQUIRE, __HIP_MEMORY_SCOPE_WORKGROUP) < t) {
                if (++g > 100000000) break;   // fail-safe
            }
        }

        // ---- B-operand h-fragments from shared LDS: row bA, col quad*8+ks*32 ----
        short8 afr[16];
        {
            const char* rb = tb + bA * 1024;
#pragma unroll
            for (int ks = 0; ks < 16; ++ks)
                afr[ks] = *(const short8*)(rb + ((quad * 16 + ks * 64) ^ (bA << 4)));
        }

        // ---- h-MFMAs: S^T = W-frag x h-frag, 2 chains (proven depth) ----
        floatx4 p = px, q = qx;
#pragma unroll
        for (int ks = 0; ks < 16; ks += 2) {
            p = __builtin_amdgcn_mfma_f32_16x16x32_bf16(bfr[ks],     afr[ks],     p, 0, 0, 0);
            q = __builtin_amdgcn_mfma_f32_16x16x32_bf16(bfr[ks + 1], afr[ks + 1], q, 0, 0, 0);
        }
        floatx4 acc = p + q;

        // ---- gate math fully in-lane: acc[r] = gate r (i,j,f,o) ----
        cst = sigf(acc[2] + bf) * cst + sigf(acc[0] + bi) * tanh_(acc[1] + bj);
        float h = sigf(acc[3] + bo) * tanh_(cst);

        // pack across quad pairs (cols quad, quad^1) -> u32 store:
        // per row two u32 at cols wv*4+{0,2} (8B contiguous), 16 active lanes
        float hq = __shfl_xor(h, 16, 64);
        if ((quad & 1) == 0 && l16 < 8) {
            u32 pk = ((u32)f2bf(hq) << 16) | (u32)f2bf(h);
            *(u32*)(hs + ((size_t)(t + 1) * 64 + b0 + l16) * H_ + hc) = pk;
        }

#pragma unroll
        for (int ks = 0; ks < 4; ++ks) xcur[ks] = xnxt[ks];
    }
}

// decoder + loss: rows R = t*64+b of hs[1..512]; 32 rows/block staged in LDS
__global__ __launch_bounds__(256) void k_dec(const u16* __restrict__ hs, const float* __restrict__ Wd,
                                             const float* __restrict__ bd, const float* __restrict__ Y,
                                             float* __restrict__ out) {
    __shared__ u16 sH[32 * H_];
    __shared__ float red[4];
    int tid = threadIdx.x;
    int R0 = blockIdx.x * 32;
    for (int u = tid; u < 2048; u += 256) {
        int row = u >> 6, ch = u & 63;
        *(short8*)(sH + row * H_ + ch * 8) =
            *(const short8*)(hs + (size_t)(64 + R0 + row) * H_ + ch * 8);
    }
    __syncthreads();

    int n = tid & 127, half = tid >> 7;
    float bdv = bd[n];
    float acc[16];
#pragma unroll
    for (int i = 0; i < 16; ++i) acc[i] = 0.f;

    for (int ko = 0; ko < H_ / 8; ++ko) {
        float wv[8];
#pragma unroll
        for (int j = 0; j < 8; ++j) wv[j] = Wd[(ko * 8 + j) * N_ + n];
#pragma unroll
        for (int i = 0; i < 16; ++i) {
            int r = half * 16 + i;
            const uint4 hv = *(const uint4*)(sH + r * H_ + ko * 8);
            acc[i] += __uint_as_float(hv.x << 16) * wv[0] + __uint_as_float(hv.x & 0xFFFF0000u) * wv[1]
                    + __uint_as_float(hv.y << 16) * wv[2] + __uint_as_float(hv.y & 0xFFFF0000u) * wv[3]
                    + __uint_as_float(hv.z << 16) * wv[4] + __uint_as_float(hv.z & 0xFFFF0000u) * wv[5]
                    + __uint_as_float(hv.w << 16) * wv[6] + __uint_as_float(hv.w & 0xFFFF0000u) * wv[7];
        }
    }
    float sse = 0.f;
#pragma unroll
    for (int i = 0; i < 16; ++i) {
        int R = R0 + half * 16 + i;
        int t = R >> 6, b = R & 63;
        float logit = sigf(acc[i] + bdv);
        float d = Y[(size_t)(b * T_ + t) * N_ + n] - logit;
        sse += d * d;
    }
    for (int off = 32; off > 0; off >>= 1) sse += __shfl_down(sse, off, 64);
    if ((tid & 63) == 0) red[tid >> 6] = sse;
    __syncthreads();
    if (tid == 0) {
        float tot = red[0] + red[1] + red[2] + red[3];
        atomicAdd(out, tot * (100.0f / 4194304.0f));
    }
}

extern "C" void kernel_launch(void* const* d_in, const int* in_sizes, int n_in,
                              void* d_out, int out_size, void* d_ws, size_t ws_size,
                              hipStream_t stream) {
    (void)in_sizes; (void)n_in; (void)out_size;
    const float* X  = (const float*)d_in[0];
    const float* Y  = (const float*)d_in[1];
    const float* Wx = (const float*)d_in[2];
    const float* Wh = (const float*)d_in[3];
    const float* bb = (const float*)d_in[4];
    const float* Wd = (const float*)d_in[5];
    const float* bd = (const float*)d_in[6];

    char* ws = (char*)d_ws;
    u32* syncz = (u32*)ws;
    const size_t sync_bytes = 131072;
    u16* hs  = (u16*)(ws + sync_bytes);
    const size_t hs_bytes = (size_t)(T_ + 1) * 64 * H_ * 2;   // 33,619,968
    u16* Xb  = (u16*)(ws + sync_bytes + hs_bytes);
    const size_t xb_bytes = (size_t)T_ * 64 * N_ * 2;         // 8,388,608
    u16* Wt  = (u16*)(ws + sync_bytes + hs_bytes + xb_bytes);
    const size_t need = sync_bytes + hs_bytes + xb_bytes + (size_t)2048 * KDIM * 2;
    if (ws_size < need) return;   // ~44.8 MB scratch required

    (void)hipMemsetAsync(syncz, 0, 65536, stream);            // org counters
    (void)hipMemsetAsync(hs, 0, 64 * H_ * 2, stream);         // h_{-1} = 0 (t=0 rows, NOT NaN)
    (void)hipMemsetAsync(d_out, 0, sizeof(float), stream);

    // NaN-sentinel prefill of hs rows [64, 513*64): 2,097,152 uint4 = 33.5 MB
    k_fill<<<dim3(8192), dim3(256), 0, stream>>>((uint4*)(hs + (size_t)64 * H_));

    k_xb<<<dim3((B_ * T_ * N_) / 256), dim3(256), 0, stream>>>(X, Xb);
    k_wcat<<<dim3((2048 * KDIM) / 256), dim3(256), 0, stream>>>(Wx, Wh, Wt);

    void* args[] = { (void*)&Wt, (void*)&Xb, (void*)&hs, (void*)&bb, (void*)&syncz };
    (void)hipLaunchCooperativeKernel((const void*)k_lstm, dim3(256), dim3(256), args, 0, stream);

    k_dec<<<dim3((B_ * T_) / 32), dim3(256), 0, stream>>>(hs, Wd, bd, Y, (float*)d_out);
}